// Round 10
// baseline (596.801 us; speedup 1.0000x reference)
//
#include <hip/hip_runtime.h>

#define IN 128
#define OUT 200
#define NT 13            // ceil(200/16) col-tiles
#define MT 64            // M rows per GEMM block (4 waves x 16 rows)
#define RANGES 8
#define REPLICAS 8
#define RBMAX 6272       // max nodes per range (N=50000 -> 6250)

typedef __bf16 bf16x8 __attribute__((ext_vector_type(8)));
typedef float f32x4 __attribute__((ext_vector_type(4)));
typedef unsigned short ushort;
typedef ushort ushort8 __attribute__((ext_vector_type(8)));
typedef unsigned int uint;

__device__ inline ushort f2bf(float f) {          // RNE f32 -> bf16 bits
  uint b = __float_as_uint(f);
  return (ushort)((b + 0x7FFFu + ((b >> 16) & 1u)) >> 16);
}
__device__ inline float bf_lo(uint v) { return __uint_as_float(v << 16); }
__device__ inline float bf_hi(uint v) { return __uint_as_float(v & 0xFFFF0000u); }

// packed A layout: for (row r, ch k): rt=r>>4, lr=r&15, kk=k>>5, hi=(k&31)>>3, j=k&7
__device__ inline size_t pk_idx(int row, int ch) {
  int rt = row >> 4, lr = row & 15, kk = ch >> 5, hi = (ch & 31) >> 3;
  return ((size_t)(rt * 4 + kk) * 64 + hi * 16 + lr) * 8 + (ch & 7);
}

// async global->LDS, 16B per lane; lds dst is wave-uniform base + lane*16
__device__ inline void gload16(const void* g, void* l) {
  __builtin_amdgcn_global_load_lds(
      (const __attribute__((address_space(1))) void*)g,
      (__attribute__((address_space(3))) void*)l, 16, 0, 0);
}

// ---------------- graph preprocessing (NO global atomics) ----------------
// grid = RANGES x REPLICAS blocks. Block (range, rep) scans edge slice rep and
// accumulates deg/cnt for nodes in its range in LDS, then writes its partial
// histogram coalesced. Global atomics write through to memory-side fabric on
// gfx950 (R9 evidence: WRITE_SIZE == E*64B regardless of privatization), so
// they must be eliminated, not localized.

__global__ __launch_bounds__(256) void k_hist(
    const int* __restrict__ src, const int* __restrict__ dst,
    const float* __restrict__ w, float* __restrict__ deg_part,
    int* __restrict__ cnt_part, int E, int N, int RB, int SL) {
  __shared__ float degL[RBMAX];
  __shared__ int cntL[RBMAX];
  int range = blockIdx.x / REPLICAS;
  int rep = blockIdx.x % REPLICAS;
  int base = range * RB;
  int lim = min(N - base, RB);
  for (int i = threadIdx.x; i < RB; i += 256) { degL[i] = 0.f; cntL[i] = 0; }
  __syncthreads();
  int e0 = rep * SL, e1 = min(E, e0 + SL);
  for (int e = e0 + (int)threadIdx.x; e < e1; e += 256) {
    int s = src[e], d = dst[e];
    int sl = s - base, dl = d - base;
    if ((unsigned)sl < (unsigned)lim) atomicAdd(&degL[sl], w[e]);
    if ((unsigned)dl < (unsigned)lim) atomicAdd(&cntL[dl], 1);
  }
  __syncthreads();
  for (int i = threadIdx.x; i < lim; i += 256) {
    deg_part[(size_t)rep * N + base + i] = degL[i];
    cnt_part[(size_t)rep * N + base + i] = cntL[i];
  }
}

// reduce REPLICAS partials -> dis + per-replica prefix bases + block scan of totals
__global__ void k_dis_scan(const float* __restrict__ deg_part, const int* __restrict__ cnt_part,
                           float* __restrict__ dis, int* __restrict__ pref8,
                           int* __restrict__ offs, int* __restrict__ bsum, int n) {
  __shared__ int s[256];
  int t = threadIdx.x;
  int i = blockIdx.x * 256 + t;
  int v = 0;
  if (i < n) {
    float d = 0.f;
    int run = 0;
#pragma unroll
    for (int c = 0; c < REPLICAS; ++c) {
      pref8[(size_t)c * n + i] = run;
      run += cnt_part[(size_t)c * n + i];
      d += deg_part[(size_t)c * n + i];
    }
    v = run;
    dis[i] = d > 0.f ? rsqrtf(d) : 0.f;
  }
  s[t] = v;
  __syncthreads();
  for (int o = 1; o < 256; o <<= 1) {
    int a = (t >= o) ? s[t - o] : 0;
    __syncthreads();
    s[t] += a;
    __syncthreads();
  }
  if (i < n) offs[i] = s[t] - v;
  if (t == 255) bsum[blockIdx.x] = s[255];
}

// each block computes its own prefix of bsum, then offsets its slice
__global__ void k_scan_c2(int* __restrict__ offs, const int* __restrict__ bsum,
                          int n, int E) {
  __shared__ int red[256];
  int t = threadIdx.x;
  int partial = 0;
  for (int i = t; i < (int)blockIdx.x; i += 256) partial += bsum[i];
  red[t] = partial;
  __syncthreads();
  for (int o = 128; o > 0; o >>= 1) {
    if (t < o) red[t] += red[t + o];
    __syncthreads();
  }
  int base = red[0];
  int i = blockIdx.x * 256 + t;
  if (i < n) offs[i] += base;
  if (i == 0) offs[n] = E;
}

// fill CSR records via LDS cursors (same range x replica geometry; NO global atomics)
__global__ __launch_bounds__(256) void k_fill(
    const int* __restrict__ src, const int* __restrict__ dst,
    const float* __restrict__ w, const float* __restrict__ dis,
    const int* __restrict__ offs, const int* __restrict__ pref8,
    int2* __restrict__ csr_rec, int E, int N, int RB, int SL) {
  __shared__ int curL[RBMAX];
  int range = blockIdx.x / REPLICAS;
  int rep = blockIdx.x % REPLICAS;
  int base = range * RB;
  int lim = min(N - base, RB);
  for (int i = threadIdx.x; i < RB; i += 256) curL[i] = 0;
  __syncthreads();
  int e0 = rep * SL, e1 = min(E, e0 + SL);
  for (int e = e0 + (int)threadIdx.x; e < e1; e += 256) {
    int d = dst[e];
    int dl = d - base;
    if ((unsigned)dl < (unsigned)lim) {
      int s = src[e];
      int r = atomicAdd(&curL[dl], 1);
      int pos = offs[d] + pref8[(size_t)rep * N + d] + r;
      float nm = -dis[s] * w[e] * dis[d];
      csr_rec[pos] = make_int2(s, __float_as_int(nm));
    }
  }
}

// ---------------- fused cast(x) + pack(weights, TILE-MAJOR) ----------------
// wpack frag id f = (t*6 + m)*4 + kk  -> tile t occupies contiguous 24KB

__global__ void k_cast_pack(const float* __restrict__ x, ushort* __restrict__ xb,
                            ushort* __restrict__ xp, int cast_blocks, long totx,
                            const float* __restrict__ w10, const float* __restrict__ w20,
                            const float* __restrict__ w21, const float* __restrict__ w30,
                            const float* __restrict__ w31, const float* __restrict__ w32,
                            ushort* __restrict__ wpack) {
  if (blockIdx.x < (unsigned)cast_blocks) {
    long i = ((long)blockIdx.x * blockDim.x + threadIdx.x) * 8;
    if (i >= totx) return;
    float4 a = *(const float4*)&x[i];
    float4 b = *(const float4*)&x[i + 4];
    ushort8 o;
    o[0] = f2bf(a.x); o[1] = f2bf(a.y); o[2] = f2bf(a.z); o[3] = f2bf(a.w);
    o[4] = f2bf(b.x); o[5] = f2bf(b.y); o[6] = f2bf(b.z); o[7] = f2bf(b.w);
    *(ushort8*)&xb[i] = o;
    int row = (int)(i >> 7), ch = (int)(i & 127);
    *(ushort8*)&xp[pk_idx(row, ch)] = o;
  } else {
    int gid = (blockIdx.x - cast_blocks) * blockDim.x + threadIdx.x;
    int total = 6 * NT * 4 * 64;
    if (gid >= total) return;
    int lane = gid & 63;
    int f = gid >> 6;
    int kk = f & 3;
    int g2 = f >> 2;
    int m = g2 % 6;
    int t = g2 / 6;
    const float* w = (m == 0) ? w10 : (m == 1) ? w20 : (m == 2) ? w21
                   : (m == 3) ? w30 : (m == 4) ? w31 : w32;
    int col = t * 16 + (lane & 15);
    int kbase = kk * 32 + (lane >> 4) * 8;
    ushort8 o;
#pragma unroll
    for (int j = 0; j < 8; ++j)
      o[j] = (col < OUT) ? f2bf(w[(kbase + j) * OUT + col]) : (ushort)0;
    *(ushort8*)&wpack[(size_t)gid * 8] = o;
  }
}

// ---------------- gather propagation (bf16, fp32 accum, ILP 8) ----------------

template <int MODE>
__global__ void k_gather(const ushort* __restrict__ h, const ushort* __restrict__ xb,
                         const int2* __restrict__ csr_rec,
                         const int* __restrict__ offs, ushort* __restrict__ out_lin,
                         ushort* __restrict__ out_pk, int n) {
  int node = blockIdx.x * 4 + (threadIdx.x >> 6);
  if (node >= n) return;
  int lane = threadIdx.x & 63;
  int ch0 = lane * 2;
  int s = offs[node], e = offs[node + 1];
  float lo[8], hi[8];
#pragma unroll
  for (int q = 0; q < 8; ++q) { lo[q] = 0.f; hi[q] = 0.f; }
  int p = s;
  for (; p + 7 < e; p += 8) {
    int2 rec[8]; uint v[8];
#pragma unroll
    for (int q = 0; q < 8; ++q) rec[q] = csr_rec[p + q];
#pragma unroll
    for (int q = 0; q < 8; ++q) v[q] = *(const uint*)&h[(size_t)rec[q].x * IN + ch0];
#pragma unroll
    for (int q = 0; q < 8; ++q) {
      float nm = __int_as_float(rec[q].y);
      lo[q] = fmaf(nm, bf_lo(v[q]), lo[q]);
      hi[q] = fmaf(nm, bf_hi(v[q]), hi[q]);
    }
  }
  for (; p + 1 < e; p += 2) {
    int2 r0 = csr_rec[p], r1 = csr_rec[p + 1];
    uint v0 = *(const uint*)&h[(size_t)r0.x * IN + ch0];
    uint v1 = *(const uint*)&h[(size_t)r1.x * IN + ch0];
    float n0 = __int_as_float(r0.y), n1 = __int_as_float(r1.y);
    lo[0] = fmaf(n0, bf_lo(v0), lo[0]); hi[0] = fmaf(n0, bf_hi(v0), hi[0]);
    lo[1] = fmaf(n1, bf_lo(v1), lo[1]); hi[1] = fmaf(n1, bf_hi(v1), hi[1]);
  }
  if (p < e) {
    int2 r0 = csr_rec[p];
    float n0 = __int_as_float(r0.y);
    uint v0 = *(const uint*)&h[(size_t)r0.x * IN + ch0];
    lo[2] = fmaf(n0, bf_lo(v0), lo[2]); hi[2] = fmaf(n0, bf_hi(v0), hi[2]);
  }
  float r0 = ((lo[0] + lo[1]) + (lo[2] + lo[3])) + ((lo[4] + lo[5]) + (lo[6] + lo[7]));
  float r1 = ((hi[0] + hi[1]) + (hi[2] + hi[3])) + ((hi[4] + hi[5]) + (hi[6] + hi[7]));
  if (MODE == 1) {
    uint xv = *(const uint*)&xb[(size_t)node * IN + ch0];
    r0 = 2.f * r0 - bf_lo(xv);
    r1 = 2.f * r1 - bf_hi(xv);
  }
  uint packed = (uint)f2bf(r0) | ((uint)f2bf(r1) << 16);
  if (MODE == 0)
    *(uint*)&out_lin[(size_t)node * IN + ch0] = packed;
  *(uint*)&out_pk[pk_idx(node, ch0)] = packed;
}

// ---------------- fused MFMA GEMM: s1,s2,s3 (R8 structure, proven) ----------------

__global__ __launch_bounds__(256) void k_gemm_mfma(
    const ushort* __restrict__ xp, const ushort* __restrict__ t1p, const ushort* __restrict__ t2p,
    const ushort* __restrict__ wpack,
    const float* __restrict__ b1v, const float* __restrict__ b2v, const float* __restrict__ b3v,
    float* __restrict__ out, int n) {
  __shared__ ushort bsm[2][24 * 512];   // 2 x 24KB B tiles
  int lane = threadIdx.x & 63;
  int wave = threadIdx.x >> 6;
  int row0 = blockIdx.x * MT + wave * 16;
  int rt = row0 >> 4;

  bf16x8 a[3][4];
  const ushort* mats[3] = {xp, t1p, t2p};
#pragma unroll
  for (int m = 0; m < 3; ++m) {
#pragma unroll
    for (int kk = 0; kk < 4; ++kk) {
      size_t fi = ((size_t)rt * 4 + kk) * 512 + (size_t)lane * 8;
      a[m][kk] = __builtin_bit_cast(bf16x8, *(const ushort8*)&mats[m][fi]);
    }
  }
#pragma unroll
  for (int m = 0; m < 3; ++m)
#pragma unroll
    for (int kk = 0; kk < 4; ++kk)
      asm volatile("" : "+v"(a[m][kk]));   // defeat load rematerialization

  long NS = (long)n * OUT;
  float* out1 = out;
  float* out2 = out + NS;
  float* out3 = out + 2 * NS;

  auto stage = [&](int t, int buf) {
    const ushort* src = wpack + (size_t)t * 24 * 512;
#pragma unroll
    for (int j = 0; j < 6; ++j) {
      int c = wave * 6 + j;
      gload16(src + (size_t)c * 512 + (size_t)lane * 8, &bsm[buf][c * 512]);
    }
  };

  stage(0, 0);
  __syncthreads();
  int cur = 0;

  for (int t = 0; t < NT; ++t) {
    if (t + 1 < NT) stage(t + 1, cur ^ 1);

    int col = t * 16 + (lane & 15);
    bool colok = col < OUT;
    int colc = colok ? col : 0;
    float bb1 = colok ? b1v[colc] : 0.f;
    float bb2 = colok ? b2v[colc] : 0.f;
    float bb3 = colok ? b3v[colc] : 0.f;
    f32x4 c1 = {bb1, bb1, bb1, bb1};
    f32x4 c2 = {bb2, bb2, bb2, bb2};
    f32x4 c3 = {bb3, bb3, bb3, bb3};

    const ushort* bb = &bsm[cur][0];
#pragma unroll
    for (int kk = 0; kk < 4; ++kk) {
      bf16x8 b10 = __builtin_bit_cast(bf16x8, *(const ushort8*)&bb[(0 * 4 + kk) * 512 + lane * 8]);
      bf16x8 b20 = __builtin_bit_cast(bf16x8, *(const ushort8*)&bb[(1 * 4 + kk) * 512 + lane * 8]);
      bf16x8 b21 = __builtin_bit_cast(bf16x8, *(const ushort8*)&bb[(2 * 4 + kk) * 512 + lane * 8]);
      bf16x8 b30 = __builtin_bit_cast(bf16x8, *(const ushort8*)&bb[(3 * 4 + kk) * 512 + lane * 8]);
      bf16x8 b31 = __builtin_bit_cast(bf16x8, *(const ushort8*)&bb[(4 * 4 + kk) * 512 + lane * 8]);
      bf16x8 b32 = __builtin_bit_cast(bf16x8, *(const ushort8*)&bb[(5 * 4 + kk) * 512 + lane * 8]);
      c1 = __builtin_amdgcn_mfma_f32_16x16x32_bf16(a[0][kk], b10, c1, 0, 0, 0);
      c2 = __builtin_amdgcn_mfma_f32_16x16x32_bf16(a[0][kk], b20, c2, 0, 0, 0);
      c2 = __builtin_amdgcn_mfma_f32_16x16x32_bf16(a[1][kk], b21, c2, 0, 0, 0);
      c3 = __builtin_amdgcn_mfma_f32_16x16x32_bf16(a[0][kk], b30, c3, 0, 0, 0);
      c3 = __builtin_amdgcn_mfma_f32_16x16x32_bf16(a[1][kk], b31, c3, 0, 0, 0);
      c3 = __builtin_amdgcn_mfma_f32_16x16x32_bf16(a[2][kk], b32, c3, 0, 0, 0);
    }

    if (colok) {
      int rbase = row0 + (lane >> 4) * 4;
#pragma unroll
      for (int r = 0; r < 4; ++r) {
        int ra = rbase + r;
        if (ra < n) {
          out1[(long)ra * OUT + col] = c1[r];
          out2[(long)ra * OUT + col] = c2[r];
          out3[(long)ra * OUT + col] = c3[r];
        }
      }
    }

    __syncthreads();
    cur ^= 1;
  }
}

// ---------------- launch ----------------

extern "C" void kernel_launch(void* const* d_in, const int* in_sizes, int n_in,
                              void* d_out, int out_size, void* d_ws, size_t ws_size,
                              hipStream_t stream) {
  const float* x   = (const float*)d_in[0];
  const int*   ei  = (const int*)d_in[1];
  const float* ew  = (const float*)d_in[2];
  const float* w10 = (const float*)d_in[3];
  const float* b1  = (const float*)d_in[4];
  const float* w20 = (const float*)d_in[5];
  const float* w21 = (const float*)d_in[6];
  const float* b2  = (const float*)d_in[7];
  const float* w30 = (const float*)d_in[8];
  const float* w31 = (const float*)d_in[9];
  const float* w32 = (const float*)d_in[10];
  const float* b3  = (const float*)d_in[11];
  float* out = (float*)d_out;

  int N = in_sizes[0] / IN;
  int E = in_sizes[2];
  const int* src = ei;
  const int* dst = ei + E;

  int mtiles = (N + MT - 1) / MT;           // 782
  size_t prow = (size_t)mtiles * MT;        // padded rows
  size_t pksz = prow * IN * 2;              // bytes per packed matrix

  int RB = (N + RANGES - 1) / RANGES;       // 6250 (<= RBMAX)
  int SL = (E + REPLICAS - 1) / REPLICAS;   // 100000

  char* ws = (char*)d_ws;
  size_t off = 0;
  auto alloc = [&](size_t bytes) {
    void* p = ws + off;
    off = (off + bytes + 15) & ~(size_t)15;
    return p;
  };
  float* deg_part = (float*)alloc((size_t)REPLICAS * N * 4);
  int*   cnt_part = (int*)alloc((size_t)REPLICAS * N * 4);
  int*   pref8    = (int*)alloc((size_t)REPLICAS * N * 4);
  float* dis      = (float*)alloc((size_t)N * 4);
  int*   offs     = (int*)alloc(((size_t)N + 1) * 4);
  int2*  csr_rec  = (int2*)alloc((size_t)E * 8);
  int*   bsum     = (int*)alloc(256 * 4);
  ushort* xb      = (ushort*)alloc((size_t)N * IN * 2);   // linear
  ushort* tx1b    = (ushort*)alloc((size_t)N * IN * 2);   // linear
  ushort* xp      = (ushort*)alloc(pksz);                 // packed
  ushort* t1p     = (ushort*)alloc(pksz);
  ushort* t2p     = (ushort*)alloc(pksz);
  ushort* wpack   = (ushort*)alloc((size_t)6 * NT * 4 * 64 * 8 * 2);

  const int tb = 256;
  int nb = (N + 255) / 256;

  long totx = (long)N * IN;
  int cast_blocks = (int)((totx / 8 + tb - 1) / tb);
  int wp_blocks = (6 * NT * 4 * 64 + tb - 1) / tb;

  k_hist<<<RANGES * REPLICAS, 256, 0, stream>>>(src, dst, ew, deg_part, cnt_part, E, N, RB, SL);
  k_dis_scan<<<nb, 256, 0, stream>>>(deg_part, cnt_part, dis, pref8, offs, bsum, N);
  k_scan_c2<<<nb, 256, 0, stream>>>(offs, bsum, N, E);
  k_fill<<<RANGES * REPLICAS, 256, 0, stream>>>(src, dst, ew, dis, offs, pref8, csr_rec, E, N, RB, SL);
  k_cast_pack<<<cast_blocks + wp_blocks, tb, 0, stream>>>(
      x, xb, xp, cast_blocks, totx, w10, w20, w21, w30, w31, w32, wpack);

  int gblk = (N + 3) / 4;
  k_gather<0><<<gblk, 256, 0, stream>>>(xb, xb, csr_rec, offs, tx1b, t1p, N);
  k_gather<1><<<gblk, 256, 0, stream>>>(tx1b, xb, csr_rec, offs, nullptr, t2p, N);

  k_gemm_mfma<<<mtiles, 256, 0, stream>>>(xp, t1p, t2p, wpack, b1, b2, b3, out, N);
}

// Round 11
// 238.052 us; speedup vs baseline: 2.5070x; 2.5070x over previous
//
#include <hip/hip_runtime.h>

#define IN 128
#define OUT 200
#define NT 13            // ceil(200/16) col-tiles
#define MT 64            // M rows per GEMM block (4 waves x 16 rows)
#define RANGES 8
#define REPLICAS 64
#define RBMAX 6272       // max nodes per range (N=50000 -> 6250)

typedef __bf16 bf16x8 __attribute__((ext_vector_type(8)));
typedef float f32x4 __attribute__((ext_vector_type(4)));
typedef unsigned short ushort;
typedef ushort ushort8 __attribute__((ext_vector_type(8)));
typedef unsigned int uint;

__device__ inline ushort f2bf(float f) {          // RNE f32 -> bf16 bits
  uint b = __float_as_uint(f);
  return (ushort)((b + 0x7FFFu + ((b >> 16) & 1u)) >> 16);
}
__device__ inline float bf_lo(uint v) { return __uint_as_float(v << 16); }
__device__ inline float bf_hi(uint v) { return __uint_as_float(v & 0xFFFF0000u); }

// packed A layout: for (row r, ch k): rt=r>>4, lr=r&15, kk=k>>5, hi=(k&31)>>3, j=k&7
__device__ inline size_t pk_idx(int row, int ch) {
  int rt = row >> 4, lr = row & 15, kk = ch >> 5, hi = (ch & 31) >> 3;
  return ((size_t)(rt * 4 + kk) * 64 + hi * 16 + lr) * 8 + (ch & 7);
}

// async global->LDS, 16B per lane; lds dst is wave-uniform base + lane*16
__device__ inline void gload16(const void* g, void* l) {
  __builtin_amdgcn_global_load_lds(
      (const __attribute__((address_space(1))) void*)g,
      (__attribute__((address_space(3))) void*)l, 16, 0, 0);
}

// ---------------- graph preprocessing (NO global atomics, 512-block geometry) ----------------
// grid = RANGES x REPLICAS = 512 blocks. Block (range, rep) scans edge slice rep
// (12.5k edges) and accumulates deg/cnt for its node range in LDS, then writes
// its partial histogram coalesced. R9 evidence: global atomics write through to
// the memory-side fabric (WRITE_SIZE == E*64B) -> eliminated, not localized.
// R10 lesson: 64 blocks starved the chip; 512 blocks restore parallelism.

__global__ __launch_bounds__(256) void k_hist(
    const int* __restrict__ src, const int* __restrict__ dst,
    const float* __restrict__ w, float* __restrict__ deg_part,
    int* __restrict__ cnt_part, int E, int N, int RB, int SL) {
  __shared__ float degL[RBMAX];
  __shared__ int cntL[RBMAX];
  int range = blockIdx.x / REPLICAS;
  int rep = blockIdx.x % REPLICAS;
  int base = range * RB;
  int lim = min(N - base, RB);
  for (int i = threadIdx.x; i < RB; i += 256) { degL[i] = 0.f; cntL[i] = 0; }
  __syncthreads();
  int e0 = rep * SL, e1 = min(E, e0 + SL);
  for (int e = e0 + (int)threadIdx.x; e < e1; e += 256) {
    int s = src[e], d = dst[e];
    int sl = s - base, dl = d - base;
    if ((unsigned)sl < (unsigned)lim) atomicAdd(&degL[sl], w[e]);
    if ((unsigned)dl < (unsigned)lim) atomicAdd(&cntL[dl], 1);
  }
  __syncthreads();
  for (int i = threadIdx.x; i < lim; i += 256) {
    deg_part[(size_t)rep * N + base + i] = degL[i];
    cnt_part[(size_t)rep * N + base + i] = cntL[i];
  }
}

// reduce REPLICAS partials -> dis + per-replica prefix (IN-PLACE over cnt_part)
// + block-level scan of per-node totals
__global__ void k_dis_scan(const float* __restrict__ deg_part, int* __restrict__ cnt_part,
                           float* __restrict__ dis,
                           int* __restrict__ offs, int* __restrict__ bsum, int n) {
  __shared__ int s[256];
  int t = threadIdx.x;
  int i = blockIdx.x * 256 + t;
  int v = 0;
  if (i < n) {
    float d = 0.f;
    int run = 0;
    for (int c = 0; c < REPLICAS; ++c) {
      size_t idx = (size_t)c * n + i;
      int cv = cnt_part[idx];
      cnt_part[idx] = run;          // becomes per-replica prefix base
      run += cv;
      d += deg_part[idx];
    }
    v = run;
    dis[i] = d > 0.f ? rsqrtf(d) : 0.f;
  }
  s[t] = v;
  __syncthreads();
  for (int o = 1; o < 256; o <<= 1) {
    int a = (t >= o) ? s[t - o] : 0;
    __syncthreads();
    s[t] += a;
    __syncthreads();
  }
  if (i < n) offs[i] = s[t] - v;
  if (t == 255) bsum[blockIdx.x] = s[255];
}

// each block computes its own prefix of bsum, then offsets its slice
__global__ void k_scan_c2(int* __restrict__ offs, const int* __restrict__ bsum,
                          int n, int E) {
  __shared__ int red[256];
  int t = threadIdx.x;
  int partial = 0;
  for (int i = t; i < (int)blockIdx.x; i += 256) partial += bsum[i];
  red[t] = partial;
  __syncthreads();
  for (int o = 128; o > 0; o >>= 1) {
    if (t < o) red[t] += red[t + o];
    __syncthreads();
  }
  int base = red[0];
  int i = blockIdx.x * 256 + t;
  if (i < n) offs[i] += base;
  if (i == 0) offs[n] = E;
}

// fill CSR records via LDS cursors (same 512-block geometry; NO global atomics)
__global__ __launch_bounds__(256) void k_fill(
    const int* __restrict__ src, const int* __restrict__ dst,
    const float* __restrict__ w, const float* __restrict__ dis,
    const int* __restrict__ offs, const int* __restrict__ pref,
    int2* __restrict__ csr_rec, int E, int N, int RB, int SL) {
  __shared__ int curL[RBMAX];
  int range = blockIdx.x / REPLICAS;
  int rep = blockIdx.x % REPLICAS;
  int base = range * RB;
  int lim = min(N - base, RB);
  for (int i = threadIdx.x; i < RB; i += 256) curL[i] = 0;
  __syncthreads();
  int e0 = rep * SL, e1 = min(E, e0 + SL);
  for (int e = e0 + (int)threadIdx.x; e < e1; e += 256) {
    int d = dst[e];
    int dl = d - base;
    if ((unsigned)dl < (unsigned)lim) {
      int s = src[e];
      int r = atomicAdd(&curL[dl], 1);
      int pos = offs[d] + pref[(size_t)rep * N + d] + r;
      float nm = -dis[s] * w[e] * dis[d];
      csr_rec[pos] = make_int2(s, __float_as_int(nm));
    }
  }
}

// ---------------- fused cast(x) + pack(weights, TILE-MAJOR) ----------------
// wpack frag id f = (t*6 + m)*4 + kk  -> tile t occupies contiguous 24KB

__global__ void k_cast_pack(const float* __restrict__ x, ushort* __restrict__ xb,
                            ushort* __restrict__ xp, int cast_blocks, long totx,
                            const float* __restrict__ w10, const float* __restrict__ w20,
                            const float* __restrict__ w21, const float* __restrict__ w30,
                            const float* __restrict__ w31, const float* __restrict__ w32,
                            ushort* __restrict__ wpack) {
  if (blockIdx.x < (unsigned)cast_blocks) {
    long i = ((long)blockIdx.x * blockDim.x + threadIdx.x) * 8;
    if (i >= totx) return;
    float4 a = *(const float4*)&x[i];
    float4 b = *(const float4*)&x[i + 4];
    ushort8 o;
    o[0] = f2bf(a.x); o[1] = f2bf(a.y); o[2] = f2bf(a.z); o[3] = f2bf(a.w);
    o[4] = f2bf(b.x); o[5] = f2bf(b.y); o[6] = f2bf(b.z); o[7] = f2bf(b.w);
    *(ushort8*)&xb[i] = o;
    int row = (int)(i >> 7), ch = (int)(i & 127);
    *(ushort8*)&xp[pk_idx(row, ch)] = o;
  } else {
    int gid = (blockIdx.x - cast_blocks) * blockDim.x + threadIdx.x;
    int total = 6 * NT * 4 * 64;
    if (gid >= total) return;
    int lane = gid & 63;
    int f = gid >> 6;
    int kk = f & 3;
    int g2 = f >> 2;
    int m = g2 % 6;
    int t = g2 / 6;
    const float* w = (m == 0) ? w10 : (m == 1) ? w20 : (m == 2) ? w21
                   : (m == 3) ? w30 : (m == 4) ? w31 : w32;
    int col = t * 16 + (lane & 15);
    int kbase = kk * 32 + (lane >> 4) * 8;
    ushort8 o;
#pragma unroll
    for (int j = 0; j < 8; ++j)
      o[j] = (col < OUT) ? f2bf(w[(kbase + j) * OUT + col]) : (ushort)0;
    *(ushort8*)&wpack[(size_t)gid * 8] = o;
  }
}

// ---------------- gather propagation (bf16, fp32 accum, ILP 8) ----------------

template <int MODE>
__global__ void k_gather(const ushort* __restrict__ h, const ushort* __restrict__ xb,
                         const int2* __restrict__ csr_rec,
                         const int* __restrict__ offs, ushort* __restrict__ out_lin,
                         ushort* __restrict__ out_pk, int n) {
  int node = blockIdx.x * 4 + (threadIdx.x >> 6);
  if (node >= n) return;
  int lane = threadIdx.x & 63;
  int ch0 = lane * 2;
  int s = offs[node], e = offs[node + 1];
  float lo[8], hi[8];
#pragma unroll
  for (int q = 0; q < 8; ++q) { lo[q] = 0.f; hi[q] = 0.f; }
  int p = s;
  for (; p + 7 < e; p += 8) {
    int2 rec[8]; uint v[8];
#pragma unroll
    for (int q = 0; q < 8; ++q) rec[q] = csr_rec[p + q];
#pragma unroll
    for (int q = 0; q < 8; ++q) v[q] = *(const uint*)&h[(size_t)rec[q].x * IN + ch0];
#pragma unroll
    for (int q = 0; q < 8; ++q) {
      float nm = __int_as_float(rec[q].y);
      lo[q] = fmaf(nm, bf_lo(v[q]), lo[q]);
      hi[q] = fmaf(nm, bf_hi(v[q]), hi[q]);
    }
  }
  for (; p + 1 < e; p += 2) {
    int2 r0 = csr_rec[p], r1 = csr_rec[p + 1];
    uint v0 = *(const uint*)&h[(size_t)r0.x * IN + ch0];
    uint v1 = *(const uint*)&h[(size_t)r1.x * IN + ch0];
    float n0 = __int_as_float(r0.y), n1 = __int_as_float(r1.y);
    lo[0] = fmaf(n0, bf_lo(v0), lo[0]); hi[0] = fmaf(n0, bf_hi(v0), hi[0]);
    lo[1] = fmaf(n1, bf_lo(v1), lo[1]); hi[1] = fmaf(n1, bf_hi(v1), hi[1]);
  }
  if (p < e) {
    int2 r0 = csr_rec[p];
    float n0 = __int_as_float(r0.y);
    uint v0 = *(const uint*)&h[(size_t)r0.x * IN + ch0];
    lo[2] = fmaf(n0, bf_lo(v0), lo[2]); hi[2] = fmaf(n0, bf_hi(v0), hi[2]);
  }
  float r0 = ((lo[0] + lo[1]) + (lo[2] + lo[3])) + ((lo[4] + lo[5]) + (lo[6] + lo[7]));
  float r1 = ((hi[0] + hi[1]) + (hi[2] + hi[3])) + ((hi[4] + hi[5]) + (hi[6] + hi[7]));
  if (MODE == 1) {
    uint xv = *(const uint*)&xb[(size_t)node * IN + ch0];
    r0 = 2.f * r0 - bf_lo(xv);
    r1 = 2.f * r1 - bf_hi(xv);
  }
  uint packed = (uint)f2bf(r0) | ((uint)f2bf(r1) << 16);
  if (MODE == 0)
    *(uint*)&out_lin[(size_t)node * IN + ch0] = packed;
  *(uint*)&out_pk[pk_idx(node, ch0)] = packed;
}

// ---------------- fused MFMA GEMM: s1,s2,s3 (R8 structure, proven) ----------------

__global__ __launch_bounds__(256) void k_gemm_mfma(
    const ushort* __restrict__ xp, const ushort* __restrict__ t1p, const ushort* __restrict__ t2p,
    const ushort* __restrict__ wpack,
    const float* __restrict__ b1v, const float* __restrict__ b2v, const float* __restrict__ b3v,
    float* __restrict__ out, int n) {
  __shared__ ushort bsm[2][24 * 512];   // 2 x 24KB B tiles
  int lane = threadIdx.x & 63;
  int wave = threadIdx.x >> 6;
  int row0 = blockIdx.x * MT + wave * 16;
  int rt = row0 >> 4;

  bf16x8 a[3][4];
  const ushort* mats[3] = {xp, t1p, t2p};
#pragma unroll
  for (int m = 0; m < 3; ++m) {
#pragma unroll
    for (int kk = 0; kk < 4; ++kk) {
      size_t fi = ((size_t)rt * 4 + kk) * 512 + (size_t)lane * 8;
      a[m][kk] = __builtin_bit_cast(bf16x8, *(const ushort8*)&mats[m][fi]);
    }
  }
#pragma unroll
  for (int m = 0; m < 3; ++m)
#pragma unroll
    for (int kk = 0; kk < 4; ++kk)
      asm volatile("" : "+v"(a[m][kk]));   // defeat load rematerialization

  long NS = (long)n * OUT;
  float* out1 = out;
  float* out2 = out + NS;
  float* out3 = out + 2 * NS;

  auto stage = [&](int t, int buf) {
    const ushort* src = wpack + (size_t)t * 24 * 512;
#pragma unroll
    for (int j = 0; j < 6; ++j) {
      int c = wave * 6 + j;
      gload16(src + (size_t)c * 512 + (size_t)lane * 8, &bsm[buf][c * 512]);
    }
  };

  stage(0, 0);
  __syncthreads();
  int cur = 0;

  for (int t = 0; t < NT; ++t) {
    if (t + 1 < NT) stage(t + 1, cur ^ 1);

    int col = t * 16 + (lane & 15);
    bool colok = col < OUT;
    int colc = colok ? col : 0;
    float bb1 = colok ? b1v[colc] : 0.f;
    float bb2 = colok ? b2v[colc] : 0.f;
    float bb3 = colok ? b3v[colc] : 0.f;
    f32x4 c1 = {bb1, bb1, bb1, bb1};
    f32x4 c2 = {bb2, bb2, bb2, bb2};
    f32x4 c3 = {bb3, bb3, bb3, bb3};

    const ushort* bb = &bsm[cur][0];
#pragma unroll
    for (int kk = 0; kk < 4; ++kk) {
      bf16x8 b10 = __builtin_bit_cast(bf16x8, *(const ushort8*)&bb[(0 * 4 + kk) * 512 + lane * 8]);
      bf16x8 b20 = __builtin_bit_cast(bf16x8, *(const ushort8*)&bb[(1 * 4 + kk) * 512 + lane * 8]);
      bf16x8 b21 = __builtin_bit_cast(bf16x8, *(const ushort8*)&bb[(2 * 4 + kk) * 512 + lane * 8]);
      bf16x8 b30 = __builtin_bit_cast(bf16x8, *(const ushort8*)&bb[(3 * 4 + kk) * 512 + lane * 8]);
      bf16x8 b31 = __builtin_bit_cast(bf16x8, *(const ushort8*)&bb[(4 * 4 + kk) * 512 + lane * 8]);
      bf16x8 b32 = __builtin_bit_cast(bf16x8, *(const ushort8*)&bb[(5 * 4 + kk) * 512 + lane * 8]);
      c1 = __builtin_amdgcn_mfma_f32_16x16x32_bf16(a[0][kk], b10, c1, 0, 0, 0);
      c2 = __builtin_amdgcn_mfma_f32_16x16x32_bf16(a[0][kk], b20, c2, 0, 0, 0);
      c2 = __builtin_amdgcn_mfma_f32_16x16x32_bf16(a[1][kk], b21, c2, 0, 0, 0);
      c3 = __builtin_amdgcn_mfma_f32_16x16x32_bf16(a[0][kk], b30, c3, 0, 0, 0);
      c3 = __builtin_amdgcn_mfma_f32_16x16x32_bf16(a[1][kk], b31, c3, 0, 0, 0);
      c3 = __builtin_amdgcn_mfma_f32_16x16x32_bf16(a[2][kk], b32, c3, 0, 0, 0);
    }

    if (colok) {
      int rbase = row0 + (lane >> 4) * 4;
#pragma unroll
      for (int r = 0; r < 4; ++r) {
        int ra = rbase + r;
        if (ra < n) {
          out1[(long)ra * OUT + col] = c1[r];
          out2[(long)ra * OUT + col] = c2[r];
          out3[(long)ra * OUT + col] = c3[r];
        }
      }
    }

    __syncthreads();
    cur ^= 1;
  }
}

// ---------------- launch ----------------

extern "C" void kernel_launch(void* const* d_in, const int* in_sizes, int n_in,
                              void* d_out, int out_size, void* d_ws, size_t ws_size,
                              hipStream_t stream) {
  const float* x   = (const float*)d_in[0];
  const int*   ei  = (const int*)d_in[1];
  const float* ew  = (const float*)d_in[2];
  const float* w10 = (const float*)d_in[3];
  const float* b1  = (const float*)d_in[4];
  const float* w20 = (const float*)d_in[5];
  const float* w21 = (const float*)d_in[6];
  const float* b2  = (const float*)d_in[7];
  const float* w30 = (const float*)d_in[8];
  const float* w31 = (const float*)d_in[9];
  const float* w32 = (const float*)d_in[10];
  const float* b3  = (const float*)d_in[11];
  float* out = (float*)d_out;

  int N = in_sizes[0] / IN;
  int E = in_sizes[2];
  const int* src = ei;
  const int* dst = ei + E;

  int mtiles = (N + MT - 1) / MT;           // 782
  size_t prow = (size_t)mtiles * MT;        // padded rows
  size_t pksz = prow * IN * 2;              // bytes per packed matrix

  int RB = (N + RANGES - 1) / RANGES;       // 6250 (<= RBMAX)
  int SL = (E + REPLICAS - 1) / REPLICAS;   // 12500

  char* ws = (char*)d_ws;
  size_t off = 0;
  auto alloc = [&](size_t bytes) {
    void* p = ws + off;
    off = (off + bytes + 15) & ~(size_t)15;
    return p;
  };
  float* deg_part = (float*)alloc((size_t)REPLICAS * N * 4);
  int*   cnt_part = (int*)alloc((size_t)REPLICAS * N * 4);  // becomes pref in-place
  float* dis      = (float*)alloc((size_t)N * 4);
  int*   offs     = (int*)alloc(((size_t)N + 1) * 4);
  int2*  csr_rec  = (int2*)alloc((size_t)E * 8);
  int*   bsum     = (int*)alloc(256 * 4);
  ushort* xb      = (ushort*)alloc((size_t)N * IN * 2);   // linear
  ushort* tx1b    = (ushort*)alloc((size_t)N * IN * 2);   // linear
  ushort* xp      = (ushort*)alloc(pksz);                 // packed
  ushort* t1p     = (ushort*)alloc(pksz);
  ushort* t2p     = (ushort*)alloc(pksz);
  ushort* wpack   = (ushort*)alloc((size_t)6 * NT * 4 * 64 * 8 * 2);

  const int tb = 256;
  int nb = (N + 255) / 256;

  long totx = (long)N * IN;
  int cast_blocks = (int)((totx / 8 + tb - 1) / tb);
  int wp_blocks = (6 * NT * 4 * 64 + tb - 1) / tb;

  k_hist<<<RANGES * REPLICAS, 256, 0, stream>>>(src, dst, ew, deg_part, cnt_part, E, N, RB, SL);
  k_dis_scan<<<nb, 256, 0, stream>>>(deg_part, cnt_part, dis, offs, bsum, N);
  k_scan_c2<<<nb, 256, 0, stream>>>(offs, bsum, N, E);
  k_fill<<<RANGES * REPLICAS, 256, 0, stream>>>(src, dst, ew, dis, offs, cnt_part, csr_rec, E, N, RB, SL);
  k_cast_pack<<<cast_blocks + wp_blocks, tb, 0, stream>>>(
      x, xb, xp, cast_blocks, totx, w10, w20, w21, w30, w31, w32, wpack);

  int gblk = (N + 3) / 4;
  k_gather<0><<<gblk, 256, 0, stream>>>(xb, xb, csr_rec, offs, tx1b, t1p, N);
  k_gather<1><<<gblk, 256, 0, stream>>>(tx1b, xb, csr_rec, offs, nullptr, t2p, N);

  k_gemm_mfma<<<mtiles, 256, 0, stream>>>(xp, t1p, t2p, wpack, b1, b2, b3, out, N);
}